// Round 2
// baseline (1063.333 us; speedup 1.0000x reference)
//
#include <hip/hip_runtime.h>
#include <hip/hip_bf16.h>

// DeepSeek MLA attention forward, MI355X.
// I/O dtype is auto-detected on device (fp32 per reference, or bf16): a sniffer
// kernel votes on bit patterns of `hidden`, conversion kernels produce bf16
// working copies either way, and the final GEMM writes d_out in the same mode.
// Pipeline: conv -> gemm(q_a) -> rms -> gemm(q_b) -> gemm(kv_a) -> rms ->
//           gemm(kv_b) -> prep(RoPE) -> causal flash attention -> gemm(wo)

typedef __attribute__((ext_vector_type(8))) __bf16 bf16x8;
typedef __attribute__((ext_vector_type(4))) float f32x4;

#define MFMA_BF16(a, b, c) __builtin_amdgcn_mfma_f32_16x16x32_bf16((a), (b), (c), 0, 0, 0)

__device__ __forceinline__ void async_load16(const void* g, void* l) {
  __builtin_amdgcn_global_load_lds(
      (const __attribute__((address_space(1))) void*)g,
      (__attribute__((address_space(3))) void*)l, 16, 0, 0);
}

// ---------------------------------------------------------------------------
// Dtype sniffer: votes 1 (bf16) / 0 (fp32) into flag[0].
// Low 16-bit half of each u32: for bf16 data it's a real bf16 (exponent in a
// sane range ~always); for fp32 data it's mantissa bits (uniform exponent,
// ~25% in range). 256 samples, threshold 128.
// ---------------------------------------------------------------------------
__global__ void sniff_k(const unsigned int* __restrict__ u, int* __restrict__ flag) {
  int t = threadIdx.x;
  unsigned v = u[t];
  int e = (v >> 7) & 0xFF;  // exponent field of low half as bf16
  int s = (e >= 96 && e <= 160) ? 1 : 0;
#pragma unroll
  for (int off = 32; off >= 1; off >>= 1) s += __shfl_xor(s, off);
  __shared__ int cnt[4];
  if ((t & 63) == 0) cnt[t >> 6] = s;
  __syncthreads();
  if (t == 0) flag[0] = (cnt[0] + cnt[1] + cnt[2] + cnt[3] >= 128) ? 1 : 0;
}

// Convert input (fp32 or bf16 per flag) to bf16. n must be a multiple of 4.
__global__ void convert_k(const void* __restrict__ in, __bf16* __restrict__ out,
                          long n, const int* __restrict__ flagp) {
  const int mode = *flagp;
  const long stride = (long)gridDim.x * blockDim.x;
  for (long t = blockIdx.x * (long)blockDim.x + threadIdx.x; t * 4 < n; t += stride) {
    long i = t * 4;
    if (mode) {
      *(uint2*)(out + i) = ((const uint2*)in)[t];  // already bf16: raw copy
    } else {
      float4 v = ((const float4*)in)[t];
      out[i + 0] = (__bf16)v.x;
      out[i + 1] = (__bf16)v.y;
      out[i + 2] = (__bf16)v.z;
      out[i + 3] = (__bf16)v.w;
    }
  }
}

// ---------------------------------------------------------------------------
// GEMM: C[M,N] = A[M,K] @ B[N,K]^T.  A,B bf16 row-major.
// BM=128, BK=32, BN=128 (4 waves, 64x64 each) or BN=64.
// OUTMODE: 0 = fp32 out, 1 = bf16 out, 2 = runtime flag (1->bf16, 0->fp32).
// ---------------------------------------------------------------------------
template <int BN, int OUTMODE>
__global__ __launch_bounds__(256) void gemm_bt(
    const __bf16* __restrict__ A, const __bf16* __restrict__ B,
    void* __restrict__ Cv, const int* __restrict__ flagp,
    int M, int N, int K, int lda, int ldb, int ldc) {
  constexpr int BM = 128, BK = 32;
  constexpr int NT = (BN == 128) ? 4 : 2;
  __shared__ __align__(16) __bf16 As[BM * BK];
  __shared__ __align__(16) __bf16 Bs[BN * BK];
  const int tid = threadIdx.x;
  const int wave = tid >> 6, lane = tid & 63;
  const int m16 = lane & 15, quad = lane >> 4;
  const int m0 = blockIdx.y * BM, n0 = blockIdx.x * BN;
  const int wm = (wave >> 1) * 64;
  const int wn = (wave & 1) * (BN / 2);
  const int ar = lane >> 2;
  const int ak = (lane & 3) * 8;

  f32x4 acc[4][NT];
#pragma unroll
  for (int mt = 0; mt < 4; ++mt)
#pragma unroll
    for (int nt = 0; nt < NT; ++nt) acc[mt][nt] = (f32x4){0.f, 0.f, 0.f, 0.f};

  for (int k0 = 0; k0 < K; k0 += BK) {
#pragma unroll
    for (int c = 0; c < 2; ++c) {
      int q = wave * 2 + c;
      const __bf16* g = A + (size_t)(m0 + q * 16 + ar) * lda + k0 + ak;
      async_load16(g, (void*)(As + q * 512));
    }
    constexpr int BCH = (BN * BK) / 512;
#pragma unroll
    for (int c = 0; c < BCH / 4; ++c) {
      int q = wave * (BCH / 4) + c;
      const __bf16* g = B + (size_t)(n0 + q * 16 + ar) * ldb + k0 + ak;
      async_load16(g, (void*)(Bs + q * 512));
    }
    __syncthreads();
    bf16x8 af[4], bfv[NT];
#pragma unroll
    for (int mt = 0; mt < 4; ++mt)
      af[mt] = *(const bf16x8*)&As[(wm + mt * 16 + m16) * BK + quad * 8];
#pragma unroll
    for (int nt = 0; nt < NT; ++nt)
      bfv[nt] = *(const bf16x8*)&Bs[(wn + nt * 16 + m16) * BK + quad * 8];
#pragma unroll
    for (int mt = 0; mt < 4; ++mt)
#pragma unroll
      for (int nt = 0; nt < NT; ++nt)
        acc[mt][nt] = MFMA_BF16(af[mt], bfv[nt], acc[mt][nt]);
    __syncthreads();
  }
  bool obf16;
  if constexpr (OUTMODE == 2) obf16 = (*flagp != 0);
  else obf16 = (OUTMODE == 1);
#pragma unroll
  for (int mt = 0; mt < 4; ++mt)
#pragma unroll
    for (int nt = 0; nt < NT; ++nt)
#pragma unroll
      for (int rg = 0; rg < 4; ++rg) {
        size_t row = m0 + wm + mt * 16 + quad * 4 + rg;
        size_t col = n0 + wn + nt * 16 + m16;
        float v = acc[mt][nt][rg];
        if (obf16)
          ((__bf16*)Cv)[row * (size_t)ldc + col] = (__bf16)v;
        else
          ((float*)Cv)[row * (size_t)ldc + col] = v;
      }
}

// ---------------------------------------------------------------------------
// RMSNorm: fp32 in -> bf16 out, one block (256 thr) per row.
// ---------------------------------------------------------------------------
template <int COLS>
__global__ __launch_bounds__(256) void rms_k(const float* __restrict__ in, int ldin,
                                             const __bf16* __restrict__ w,
                                             __bf16* __restrict__ out, int ldout) {
  constexpr int PER = COLS / 256;
  const int row = blockIdx.x, tid = threadIdx.x;
  const float* x = in + (size_t)row * ldin;
  float v[PER];
  float ss = 0.f;
#pragma unroll
  for (int i = 0; i < PER; ++i) {
    v[i] = x[tid + i * 256];
    ss += v[i] * v[i];
  }
#pragma unroll
  for (int off = 32; off >= 1; off >>= 1) ss += __shfl_xor(ss, off);
  __shared__ float red[4];
  if ((tid & 63) == 0) red[tid >> 6] = ss;
  __syncthreads();
  ss = red[0] + red[1] + red[2] + red[3];
  float sc = rsqrtf(ss / (float)COLS + 1e-6f);
#pragma unroll
  for (int i = 0; i < PER; ++i)
    out[(size_t)row * ldout + tid + i * 256] =
        (__bf16)(v[i] * sc * (float)w[tid + i * 256]);
}

// ---------------------------------------------------------------------------
// Prep: build Q[bh][s][192], K[bh][s][192] with RoPE on last 64 dims.
// ---------------------------------------------------------------------------
__global__ void prep_k(const __bf16* __restrict__ qb,    // [4096][3072]
                       const float* __restrict__ ckv,    // [4096][576] fp32
                       const __bf16* __restrict__ kvb,   // [4096][4096]
                       const __bf16* __restrict__ cosp,  // [2048][64] bf16
                       const __bf16* __restrict__ sinp,
                       __bf16* __restrict__ Qg, __bf16* __restrict__ Kg) {
  const int bs = blockIdx.x;  // b*2048 + s
  const int s = bs & 2047, b = bs >> 11;
  const int d = threadIdx.x;  // 0..191
  float c = 0.f, sn = 0.f, kpe = 0.f;
  if (d >= 128) {
    int i = d - 128;
    c = (float)cosp[s * 64 + i];
    sn = (float)sinp[s * 64 + i];
    const float* ck = ckv + (size_t)bs * 576 + 512;
    if (i < 32)
      kpe = ck[2 * i] * c - ck[2 * i + 1] * sn;
    else {
      int j = i - 32;
      kpe = ck[2 * j + 1] * c + ck[2 * j] * sn;
    }
  }
  for (int h = 0; h < 16; ++h) {
    size_t orow = ((size_t)(b * 16 + h) * 2048 + s) * 192 + d;
    const __bf16* qr = qb + (size_t)bs * 3072 + h * 192;
    float qv;
    if (d < 128)
      qv = (float)qr[d];
    else {
      int i = d - 128;
      if (i < 32)
        qv = (float)qr[128 + 2 * i] * c - (float)qr[128 + 2 * i + 1] * sn;
      else {
        int j = i - 32;
        qv = (float)qr[128 + 2 * j + 1] * c + (float)qr[128 + 2 * j] * sn;
      }
    }
    Qg[orow] = (__bf16)qv;
    float kval = (d < 128) ? (float)kvb[(size_t)bs * 4096 + h * 256 + d] : kpe;
    Kg[orow] = (__bf16)kval;
  }
}

// ---------------------------------------------------------------------------
// Causal flash attention. Block = 128 q-rows x (b,h). Wave w owns q rows
// [w*32, w*32+32). K-tiles of 64. D_Q=192, D_V=128.
// ---------------------------------------------------------------------------
#define ATT_SCALE 0.07216878364870323f  // 1/sqrt(192)

__global__ __launch_bounds__(256) void attn_k(const __bf16* __restrict__ Qg,
                                              const __bf16* __restrict__ Kg,
                                              const __bf16* __restrict__ kvb,
                                              __bf16* __restrict__ Og) {
  constexpr int S = 2048;
  __shared__ __align__(16) __bf16 Ks[64 * 200];
  __shared__ __align__(16) __bf16 Vt[128 * 72];
  __shared__ __align__(16) __bf16 Ps[128 * 72];
  const int bh = blockIdx.y, b = bh >> 4, h = bh & 15;
  const int i0 = blockIdx.x * 128;
  const int tid = threadIdx.x, wave = tid >> 6, lane = tid & 63;
  const int m16 = lane & 15, quad = lane >> 4;

  bf16x8 qf[2][6];
  const __bf16* Qb = Qg + ((size_t)bh * S + i0 + wave * 32) * 192;
#pragma unroll
  for (int mt = 0; mt < 2; ++mt)
#pragma unroll
    for (int kc = 0; kc < 6; ++kc)
      qf[mt][kc] = *(const bf16x8*)(Qb + (mt * 16 + m16) * 192 + kc * 32 + quad * 8);

  f32x4 oacc[2][8];
#pragma unroll
  for (int mt = 0; mt < 2; ++mt)
#pragma unroll
    for (int nt = 0; nt < 8; ++nt) oacc[mt][nt] = (f32x4){0.f, 0.f, 0.f, 0.f};
  float mrow[2][4], lrow[2][4];
#pragma unroll
  for (int mt = 0; mt < 2; ++mt)
#pragma unroll
    for (int rg = 0; rg < 4; ++rg) {
      mrow[mt][rg] = -1e30f;
      lrow[mt][rg] = 0.f;
    }

  const int ntl = (i0 >> 6) + 2;
  for (int t = 0; t < ntl; ++t) {
    const int kt0 = t * 64;
    const __bf16* Kb = Kg + ((size_t)bh * S + kt0) * 192;
#pragma unroll
    for (int c2 = 0; c2 < 6; ++c2) {
      int chunk = tid + c2 * 256;
      int r = chunk / 24, col = (chunk % 24) * 8;
      *(bf16x8*)&Ks[r * 200 + col] = *(const bf16x8*)(Kb + r * 192 + col);
    }
    const __bf16* Vb = kvb + ((size_t)(b * S + kt0)) * 4096 + h * 256 + 128;
#pragma unroll
    for (int c2 = 0; c2 < 4; ++c2) {
      int chunk = tid + c2 * 256;
      int r = chunk >> 4, d0 = (chunk & 15) * 8;
      bf16x8 v = *(const bf16x8*)(Vb + (size_t)r * 4096 + d0);
#pragma unroll
      for (int j = 0; j < 8; ++j) Vt[(d0 + j) * 72 + r] = v[j];
    }
    __syncthreads();

    f32x4 sacc[2][4];
#pragma unroll
    for (int mt = 0; mt < 2; ++mt)
#pragma unroll
      for (int nt = 0; nt < 4; ++nt) sacc[mt][nt] = (f32x4){0.f, 0.f, 0.f, 0.f};
#pragma unroll
    for (int kc = 0; kc < 6; ++kc) {
      bf16x8 bv[4];
#pragma unroll
      for (int nt = 0; nt < 4; ++nt)
        bv[nt] = *(const bf16x8*)&Ks[(nt * 16 + m16) * 200 + kc * 32 + quad * 8];
#pragma unroll
      for (int nt = 0; nt < 4; ++nt)
#pragma unroll
        for (int mt = 0; mt < 2; ++mt)
          sacc[mt][nt] = MFMA_BF16(qf[mt][kc], bv[nt], sacc[mt][nt]);
    }
#pragma unroll
    for (int mt = 0; mt < 2; ++mt)
#pragma unroll
      for (int nt = 0; nt < 4; ++nt)
#pragma unroll
        for (int rg = 0; rg < 4; ++rg) {
          int qrow = i0 + wave * 32 + mt * 16 + quad * 4 + rg;
          int kcol = kt0 + nt * 16 + m16;
          float sv = sacc[mt][nt][rg] * ATT_SCALE;
          sacc[mt][nt][rg] = (kcol > qrow) ? -1e30f : sv;
        }
#pragma unroll
    for (int mt = 0; mt < 2; ++mt)
#pragma unroll
      for (int rg = 0; rg < 4; ++rg) {
        float tm = fmaxf(fmaxf(sacc[mt][0][rg], sacc[mt][1][rg]),
                         fmaxf(sacc[mt][2][rg], sacc[mt][3][rg]));
        tm = fmaxf(tm, __shfl_xor(tm, 1));
        tm = fmaxf(tm, __shfl_xor(tm, 2));
        tm = fmaxf(tm, __shfl_xor(tm, 4));
        tm = fmaxf(tm, __shfl_xor(tm, 8));
        float om = mrow[mt][rg];
        float nm = fmaxf(om, tm);
        float alpha = __expf(om - nm);
        mrow[mt][rg] = nm;
        float rs = 0.f;
#pragma unroll
        for (int nt = 0; nt < 4; ++nt) {
          float p = __expf(sacc[mt][nt][rg] - nm);
          sacc[mt][nt][rg] = p;
          rs += p;
        }
        rs += __shfl_xor(rs, 1);
        rs += __shfl_xor(rs, 2);
        rs += __shfl_xor(rs, 4);
        rs += __shfl_xor(rs, 8);
        lrow[mt][rg] = lrow[mt][rg] * alpha + rs;
#pragma unroll
        for (int nt = 0; nt < 8; ++nt) oacc[mt][nt][rg] *= alpha;
      }
#pragma unroll
    for (int mt = 0; mt < 2; ++mt)
#pragma unroll
      for (int nt = 0; nt < 4; ++nt)
#pragma unroll
        for (int rg = 0; rg < 4; ++rg)
          Ps[(wave * 32 + mt * 16 + quad * 4 + rg) * 72 + nt * 16 + m16] =
              (__bf16)sacc[mt][nt][rg];
#pragma unroll
    for (int kc2 = 0; kc2 < 2; ++kc2) {
      bf16x8 af[2];
#pragma unroll
      for (int mt = 0; mt < 2; ++mt)
        af[mt] = *(const bf16x8*)&Ps[(wave * 32 + mt * 16 + m16) * 72 + kc2 * 32 + quad * 8];
#pragma unroll
      for (int nt = 0; nt < 8; ++nt) {
        bf16x8 bv = *(const bf16x8*)&Vt[(nt * 16 + m16) * 72 + kc2 * 32 + quad * 8];
#pragma unroll
        for (int mt = 0; mt < 2; ++mt)
          oacc[mt][nt] = MFMA_BF16(af[mt], bv, oacc[mt][nt]);
      }
    }
    __syncthreads();
  }
#pragma unroll
  for (int mt = 0; mt < 2; ++mt)
#pragma unroll
    for (int nt = 0; nt < 8; ++nt)
#pragma unroll
      for (int rg = 0; rg < 4; ++rg) {
        int sg = i0 + wave * 32 + mt * 16 + quad * 4 + rg;
        int d = nt * 16 + m16;
        float val = oacc[mt][nt][rg] / lrow[mt][rg];
        Og[((size_t)b * S + sg) * 2048 + h * 128 + d] = (__bf16)val;
      }
}

// ---------------------------------------------------------------------------
extern "C" void kernel_launch(void* const* d_in, const int* in_sizes, int n_in,
                              void* d_out, int out_size, void* d_ws, size_t ws_size,
                              hipStream_t stream) {
  char* w0 = (char*)d_ws;
  int* flag = (int*)w0;
  char* w = w0 + 256;
  __bf16* hid_bf = (__bf16*)w;   w += (size_t)4096 * 5120 * 2;   // 41943040
  __bf16* wqa_bf = (__bf16*)w;   w += (size_t)1536 * 5120 * 2;   // 15728640
  __bf16* wqb_bf = (__bf16*)w;   w += (size_t)3072 * 1536 * 2;   // 9437184
  __bf16* wkva_bf = (__bf16*)w;  w += (size_t)576 * 5120 * 2;    // 5898240
  __bf16* wkvb_bf = (__bf16*)w;  w += (size_t)4096 * 512 * 2;    // 4194304
  __bf16* wo_bf = (__bf16*)w;    w += (size_t)5120 * 2048 * 2;   // 20971520
  __bf16* cos_bf = (__bf16*)w;   w += (size_t)2048 * 64 * 2;
  __bf16* sin_bf = (__bf16*)w;   w += (size_t)2048 * 64 * 2;
  __bf16* qln_bf = (__bf16*)w;   w += 4096;
  __bf16* kvln_bf = (__bf16*)w;  w += 4096;
  float* qa = (float*)w;         w += (size_t)4096 * 1536 * 4;
  __bf16* qan = (__bf16*)w;      w += (size_t)4096 * 1536 * 2;
  __bf16* qb = (__bf16*)w;       w += (size_t)4096 * 3072 * 2;
  float* ckv = (float*)w;        w += (size_t)4096 * 576 * 4;
  __bf16* ckvn = (__bf16*)w;     w += (size_t)4096 * 512 * 2;
  __bf16* kvb = (__bf16*)w;      w += (size_t)4096 * 4096 * 2;
  // Overlays (lifetimes verified): Qg over hid_bf (dead after gemm kv_a);
  // Kg over wqa_bf+wqb_bf (dead after gemm q_b); ao over qa (dead after rms).
  __bf16* Qg = hid_bf;
  __bf16* Kg = wqa_bf;
  __bf16* ao = (__bf16*)qa;

  sniff_k<<<1, 256, 0, stream>>>((const unsigned int*)d_in[0], flag);
  convert_k<<<1024, 256, 0, stream>>>(d_in[0], hid_bf, (long)4096 * 5120, flag);
  convert_k<<<1024, 256, 0, stream>>>(d_in[3], wqa_bf, (long)1536 * 5120, flag);
  convert_k<<<1024, 256, 0, stream>>>(d_in[5], wqb_bf, (long)3072 * 1536, flag);
  convert_k<<<1024, 256, 0, stream>>>(d_in[6], wkva_bf, (long)576 * 5120, flag);
  convert_k<<<1024, 256, 0, stream>>>(d_in[8], wkvb_bf, (long)4096 * 512, flag);
  convert_k<<<1024, 256, 0, stream>>>(d_in[9], wo_bf, (long)5120 * 2048, flag);
  convert_k<<<64, 256, 0, stream>>>(d_in[10], cos_bf, (long)2048 * 64, flag);
  convert_k<<<64, 256, 0, stream>>>(d_in[11], sin_bf, (long)2048 * 64, flag);
  convert_k<<<2, 256, 0, stream>>>(d_in[4], qln_bf, 1536, flag);
  convert_k<<<1, 256, 0, stream>>>(d_in[7], kvln_bf, 512, flag);

  gemm_bt<128, 0><<<dim3(12, 32), 256, 0, stream>>>(hid_bf, wqa_bf, qa, flag, 4096, 1536, 5120, 5120, 5120, 1536);
  rms_k<1536><<<4096, 256, 0, stream>>>(qa, 1536, qln_bf, qan, 1536);
  gemm_bt<128, 1><<<dim3(24, 32), 256, 0, stream>>>(qan, wqb_bf, qb, flag, 4096, 3072, 1536, 1536, 1536, 3072);
  gemm_bt<64, 0><<<dim3(9, 32), 256, 0, stream>>>(hid_bf, wkva_bf, ckv, flag, 4096, 576, 5120, 5120, 5120, 576);
  rms_k<512><<<4096, 256, 0, stream>>>(ckv, 576, kvln_bf, ckvn, 512);
  gemm_bt<128, 1><<<dim3(32, 32), 256, 0, stream>>>(ckvn, wkvb_bf, kvb, flag, 4096, 4096, 512, 512, 512, 4096);
  prep_k<<<4096, 192, 0, stream>>>(qb, ckv, kvb, cos_bf, sin_bf, Qg, Kg);
  attn_k<<<dim3(16, 32), 256, 0, stream>>>(Qg, Kg, kvb, ao);
  gemm_bt<128, 2><<<dim3(40, 32), 256, 0, stream>>>(ao, wo_bf, d_out, flag, 4096, 5120, 2048, 2048, 2048, 5120);
}

// Round 3
// 919.667 us; speedup vs baseline: 1.1562x; 1.1562x over previous
//
#include <hip/hip_runtime.h>
#include <hip/hip_bf16.h>

// DeepSeek MLA attention forward, MI355X.
// Round 3: attention restructured — conflict-free in-register V transpose,
// work-balanced block remap (pair tile x with 15-x at linear distance 256),
// cross-barrier register prefetch of K/V tiles.

typedef __attribute__((ext_vector_type(8))) __bf16 bf16x8;
typedef __attribute__((ext_vector_type(4))) __bf16 bf16x4;
typedef __attribute__((ext_vector_type(4))) float f32x4;

#define MFMA_BF16(a, b, c) __builtin_amdgcn_mfma_f32_16x16x32_bf16((a), (b), (c), 0, 0, 0)

__device__ __forceinline__ void async_load16(const void* g, void* l) {
  __builtin_amdgcn_global_load_lds(
      (const __attribute__((address_space(1))) void*)g,
      (__attribute__((address_space(3))) void*)l, 16, 0, 0);
}

// ---------------------------------------------------------------------------
// Dtype sniffer: votes 1 (bf16) / 0 (fp32) into flag[0].
// ---------------------------------------------------------------------------
__global__ void sniff_k(const unsigned int* __restrict__ u, int* __restrict__ flag) {
  int t = threadIdx.x;
  unsigned v = u[t];
  int e = (v >> 7) & 0xFF;
  int s = (e >= 96 && e <= 160) ? 1 : 0;
#pragma unroll
  for (int off = 32; off >= 1; off >>= 1) s += __shfl_xor(s, off);
  __shared__ int cnt[4];
  if ((t & 63) == 0) cnt[t >> 6] = s;
  __syncthreads();
  if (t == 0) flag[0] = (cnt[0] + cnt[1] + cnt[2] + cnt[3] >= 128) ? 1 : 0;
}

// Convert input (fp32 or bf16 per flag) to bf16. n must be a multiple of 4.
__global__ void convert_k(const void* __restrict__ in, __bf16* __restrict__ out,
                          long n, const int* __restrict__ flagp) {
  const int mode = *flagp;
  const long stride = (long)gridDim.x * blockDim.x;
  for (long t = blockIdx.x * (long)blockDim.x + threadIdx.x; t * 4 < n; t += stride) {
    long i = t * 4;
    if (mode) {
      *(uint2*)(out + i) = ((const uint2*)in)[t];
    } else {
      float4 v = ((const float4*)in)[t];
      out[i + 0] = (__bf16)v.x;
      out[i + 1] = (__bf16)v.y;
      out[i + 2] = (__bf16)v.z;
      out[i + 3] = (__bf16)v.w;
    }
  }
}

// ---------------------------------------------------------------------------
// GEMM: C[M,N] = A[M,K] @ B[N,K]^T (m97 structure).
// OUTMODE: 0 = fp32 out, 1 = bf16 out, 2 = runtime flag (1->bf16, 0->fp32).
// ---------------------------------------------------------------------------
template <int BN, int OUTMODE>
__global__ __launch_bounds__(256) void gemm_bt(
    const __bf16* __restrict__ A, const __bf16* __restrict__ B,
    void* __restrict__ Cv, const int* __restrict__ flagp,
    int M, int N, int K, int lda, int ldb, int ldc) {
  constexpr int BM = 128, BK = 32;
  constexpr int NT = (BN == 128) ? 4 : 2;
  __shared__ __align__(16) __bf16 As[BM * BK];
  __shared__ __align__(16) __bf16 Bs[BN * BK];
  const int tid = threadIdx.x;
  const int wave = tid >> 6, lane = tid & 63;
  const int m16 = lane & 15, quad = lane >> 4;
  const int m0 = blockIdx.y * BM, n0 = blockIdx.x * BN;
  const int wm = (wave >> 1) * 64;
  const int wn = (wave & 1) * (BN / 2);
  const int ar = lane >> 2;
  const int ak = (lane & 3) * 8;

  f32x4 acc[4][NT];
#pragma unroll
  for (int mt = 0; mt < 4; ++mt)
#pragma unroll
    for (int nt = 0; nt < NT; ++nt) acc[mt][nt] = (f32x4){0.f, 0.f, 0.f, 0.f};

  for (int k0 = 0; k0 < K; k0 += BK) {
#pragma unroll
    for (int c = 0; c < 2; ++c) {
      int q = wave * 2 + c;
      const __bf16* g = A + (size_t)(m0 + q * 16 + ar) * lda + k0 + ak;
      async_load16(g, (void*)(As + q * 512));
    }
    constexpr int BCH = (BN * BK) / 512;
#pragma unroll
    for (int c = 0; c < BCH / 4; ++c) {
      int q = wave * (BCH / 4) + c;
      const __bf16* g = B + (size_t)(n0 + q * 16 + ar) * ldb + k0 + ak;
      async_load16(g, (void*)(Bs + q * 512));
    }
    __syncthreads();
    bf16x8 af[4], bfv[NT];
#pragma unroll
    for (int mt = 0; mt < 4; ++mt)
      af[mt] = *(const bf16x8*)&As[(wm + mt * 16 + m16) * BK + quad * 8];
#pragma unroll
    for (int nt = 0; nt < NT; ++nt)
      bfv[nt] = *(const bf16x8*)&Bs[(wn + nt * 16 + m16) * BK + quad * 8];
#pragma unroll
    for (int mt = 0; mt < 4; ++mt)
#pragma unroll
      for (int nt = 0; nt < NT; ++nt)
        acc[mt][nt] = MFMA_BF16(af[mt], bfv[nt], acc[mt][nt]);
    __syncthreads();
  }
  bool obf16;
  if constexpr (OUTMODE == 2) obf16 = (*flagp != 0);
  else obf16 = (OUTMODE == 1);
#pragma unroll
  for (int mt = 0; mt < 4; ++mt)
#pragma unroll
    for (int nt = 0; nt < NT; ++nt)
#pragma unroll
      for (int rg = 0; rg < 4; ++rg) {
        size_t row = m0 + wm + mt * 16 + quad * 4 + rg;
        size_t col = n0 + wn + nt * 16 + m16;
        float v = acc[mt][nt][rg];
        if (obf16)
          ((__bf16*)Cv)[row * (size_t)ldc + col] = (__bf16)v;
        else
          ((float*)Cv)[row * (size_t)ldc + col] = v;
      }
}

// ---------------------------------------------------------------------------
// RMSNorm: fp32 in -> bf16 out, one block (256 thr) per row.
// ---------------------------------------------------------------------------
template <int COLS>
__global__ __launch_bounds__(256) void rms_k(const float* __restrict__ in, int ldin,
                                             const __bf16* __restrict__ w,
                                             __bf16* __restrict__ out, int ldout) {
  constexpr int PER = COLS / 256;
  const int row = blockIdx.x, tid = threadIdx.x;
  const float* x = in + (size_t)row * ldin;
  float v[PER];
  float ss = 0.f;
#pragma unroll
  for (int i = 0; i < PER; ++i) {
    v[i] = x[tid + i * 256];
    ss += v[i] * v[i];
  }
#pragma unroll
  for (int off = 32; off >= 1; off >>= 1) ss += __shfl_xor(ss, off);
  __shared__ float red[4];
  if ((tid & 63) == 0) red[tid >> 6] = ss;
  __syncthreads();
  ss = red[0] + red[1] + red[2] + red[3];
  float sc = rsqrtf(ss / (float)COLS + 1e-6f);
#pragma unroll
  for (int i = 0; i < PER; ++i)
    out[(size_t)row * ldout + tid + i * 256] =
        (__bf16)(v[i] * sc * (float)w[tid + i * 256]);
}

// ---------------------------------------------------------------------------
// Prep: build Q[bh][s][192], K[bh][s][192] with RoPE on last 64 dims.
// ---------------------------------------------------------------------------
__global__ void prep_k(const __bf16* __restrict__ qb,    // [4096][3072]
                       const float* __restrict__ ckv,    // [4096][576] fp32
                       const __bf16* __restrict__ kvb,   // [4096][4096]
                       const __bf16* __restrict__ cosp,  // [2048][64] bf16
                       const __bf16* __restrict__ sinp,
                       __bf16* __restrict__ Qg, __bf16* __restrict__ Kg) {
  const int bs = blockIdx.x;  // b*2048 + s
  const int s = bs & 2047, b = bs >> 11;
  const int d = threadIdx.x;  // 0..191
  float c = 0.f, sn = 0.f, kpe = 0.f;
  if (d >= 128) {
    int i = d - 128;
    c = (float)cosp[s * 64 + i];
    sn = (float)sinp[s * 64 + i];
    const float* ck = ckv + (size_t)bs * 576 + 512;
    if (i < 32)
      kpe = ck[2 * i] * c - ck[2 * i + 1] * sn;
    else {
      int j = i - 32;
      kpe = ck[2 * j + 1] * c + ck[2 * j] * sn;
    }
  }
  for (int h = 0; h < 16; ++h) {
    size_t orow = ((size_t)(b * 16 + h) * 2048 + s) * 192 + d;
    const __bf16* qr = qb + (size_t)bs * 3072 + h * 192;
    float qv;
    if (d < 128)
      qv = (float)qr[d];
    else {
      int i = d - 128;
      if (i < 32)
        qv = (float)qr[128 + 2 * i] * c - (float)qr[128 + 2 * i + 1] * sn;
      else {
        int j = i - 32;
        qv = (float)qr[128 + 2 * j + 1] * c + (float)qr[128 + 2 * j] * sn;
      }
    }
    Qg[orow] = (__bf16)qv;
    float kval = (d < 128) ? (float)kvb[(size_t)bs * 4096 + h * 256 + d] : kpe;
    Kg[orow] = (__bf16)kval;
  }
}

// ---------------------------------------------------------------------------
// Causal flash attention, round-3 structure.
// Block = 128 q-rows x (b,h), remapped so blocks at linear distance 256
// (likely same CU) hold q-tiles x and 15-x (equal combined work).
// K/V tiles prefetched into registers AFTER the second barrier so the global
// loads stay in flight across the whole compute phase (no barrier drains them
// until the next iteration's first barrier).
// V transposed in-register (4s x 8d per thread) -> conflict-free b64 LDS writes.
// ---------------------------------------------------------------------------
#define ATT_SCALE 0.07216878364870323f  // 1/sqrt(192)

__global__ __launch_bounds__(256, 2) void attn_k(const __bf16* __restrict__ Qg,
                                                 const __bf16* __restrict__ Kg,
                                                 const __bf16* __restrict__ kvb,
                                                 __bf16* __restrict__ Og) {
  constexpr int S = 2048;
  __shared__ __align__(16) __bf16 Ks[64 * 200];
  __shared__ __align__(16) __bf16 Vt[128 * 72];
  __shared__ __align__(16) __bf16 Ps[128 * 72];
  // balanced remap: pair (15-k) with (k) at linear distance 256
  const int L = blockIdx.x + (blockIdx.y << 4);
  const int halfg = L >> 8, idx = L & 255;
  const int xt = halfg ? (idx >> 5) : (15 - (idx >> 5));
  const int bh = idx & 31, b = bh >> 4, h = bh & 15;
  const int i0 = xt * 128;
  const int tid = threadIdx.x, wave = tid >> 6, lane = tid & 63;
  const int m16 = lane & 15, quad = lane >> 4;
  // V-transpose thread mapping: 4 s-rows x 8 d-cols per thread
  const int sb = (tid & 15) * 4, d0 = (tid >> 4) * 8;

  // Q fragments resident in registers
  bf16x8 qf[2][6];
  const __bf16* Qb = Qg + ((size_t)bh * S + i0 + wave * 32) * 192;
#pragma unroll
  for (int mt = 0; mt < 2; ++mt)
#pragma unroll
    for (int kc = 0; kc < 6; ++kc)
      qf[mt][kc] = *(const bf16x8*)(Qb + (mt * 16 + m16) * 192 + kc * 32 + quad * 8);

  f32x4 oacc[2][8];
#pragma unroll
  for (int mt = 0; mt < 2; ++mt)
#pragma unroll
    for (int nt = 0; nt < 8; ++nt) oacc[mt][nt] = (f32x4){0.f, 0.f, 0.f, 0.f};
  float mrow[2][4], lrow[2][4];
#pragma unroll
  for (int mt = 0; mt < 2; ++mt)
#pragma unroll
    for (int rg = 0; rg < 4; ++rg) {
      mrow[mt][rg] = -1e30f;
      lrow[mt][rg] = 0.f;
    }

  const __bf16* Kbase = Kg + (size_t)bh * S * 192;
  const __bf16* Vbase = kvb + (size_t)b * S * 4096 + h * 256 + 128 + d0;
  const int ntl = 2 * xt + 2;

  // K staging geometry: 1536 chunks of 8 = 64 rows x 24 chunks
  int krow[6], kcol[6];
#pragma unroll
  for (int c = 0; c < 6; ++c) {
    int chunk = tid + c * 256;
    krow[c] = chunk / 24;
    kcol[c] = (chunk % 24) * 8;
  }

  // prefetch tile 0
  bf16x8 kr[6], vr[4];
#pragma unroll
  for (int c = 0; c < 6; ++c)
    kr[c] = *(const bf16x8*)(Kbase + (size_t)krow[c] * 192 + kcol[c]);
#pragma unroll
  for (int r = 0; r < 4; ++r)
    vr[r] = *(const bf16x8*)(Vbase + (size_t)(sb + r) * 4096);

  for (int t = 0; t < ntl; ++t) {
    const int kt0 = t * 64;
    __syncthreads();  // B1: prev compute done; also drains prefetched loads
    // regs -> LDS
#pragma unroll
    for (int c = 0; c < 6; ++c)
      *(bf16x8*)&Ks[krow[c] * 200 + kcol[c]] = kr[c];
#pragma unroll
    for (int j = 0; j < 8; ++j) {
      bf16x4 wv = {vr[0][j], vr[1][j], vr[2][j], vr[3][j]};
      *(bf16x4*)&Vt[(d0 + j) * 72 + sb] = wv;
    }
    __syncthreads();  // B2: LDS visible (no vmem in flight here)
    // prefetch tile t+1 — stays in flight across the whole compute phase
    if (t + 1 < ntl) {
      const __bf16* Kb = Kbase + (size_t)(kt0 + 64) * 192;
#pragma unroll
      for (int c = 0; c < 6; ++c)
        kr[c] = *(const bf16x8*)(Kb + (size_t)krow[c] * 192 + kcol[c]);
      const __bf16* Vb = Vbase + (size_t)(kt0 + 64) * 4096;
#pragma unroll
      for (int r = 0; r < 4; ++r)
        vr[r] = *(const bf16x8*)(Vb + (size_t)(sb + r) * 4096);
    }

    // S = Q K^T
    f32x4 sacc[2][4];
#pragma unroll
    for (int mt = 0; mt < 2; ++mt)
#pragma unroll
      for (int nt = 0; nt < 4; ++nt) sacc[mt][nt] = (f32x4){0.f, 0.f, 0.f, 0.f};
#pragma unroll
    for (int kc = 0; kc < 6; ++kc) {
      bf16x8 bv[4];
#pragma unroll
      for (int nt = 0; nt < 4; ++nt)
        bv[nt] = *(const bf16x8*)&Ks[(nt * 16 + m16) * 200 + kc * 32 + quad * 8];
#pragma unroll
      for (int nt = 0; nt < 4; ++nt)
#pragma unroll
        for (int mt = 0; mt < 2; ++mt)
          sacc[mt][nt] = MFMA_BF16(qf[mt][kc], bv[nt], sacc[mt][nt]);
    }
    // scale + causal mask
#pragma unroll
    for (int mt = 0; mt < 2; ++mt)
#pragma unroll
      for (int nt = 0; nt < 4; ++nt)
#pragma unroll
        for (int rg = 0; rg < 4; ++rg) {
          int qrow = i0 + wave * 32 + mt * 16 + quad * 4 + rg;
          int kcol2 = kt0 + nt * 16 + m16;
          float sv = sacc[mt][nt][rg] * ATT_SCALE;
          sacc[mt][nt][rg] = (kcol2 > qrow) ? -1e30f : sv;
        }
    // online softmax
#pragma unroll
    for (int mt = 0; mt < 2; ++mt)
#pragma unroll
      for (int rg = 0; rg < 4; ++rg) {
        float tm = fmaxf(fmaxf(sacc[mt][0][rg], sacc[mt][1][rg]),
                         fmaxf(sacc[mt][2][rg], sacc[mt][3][rg]));
        tm = fmaxf(tm, __shfl_xor(tm, 1));
        tm = fmaxf(tm, __shfl_xor(tm, 2));
        tm = fmaxf(tm, __shfl_xor(tm, 4));
        tm = fmaxf(tm, __shfl_xor(tm, 8));
        float om = mrow[mt][rg];
        float nm = fmaxf(om, tm);
        float alpha = __expf(om - nm);
        mrow[mt][rg] = nm;
        float rs = 0.f;
#pragma unroll
        for (int nt = 0; nt < 4; ++nt) {
          float p = __expf(sacc[mt][nt][rg] - nm);
          sacc[mt][nt][rg] = p;
          rs += p;
        }
        rs += __shfl_xor(rs, 1);
        rs += __shfl_xor(rs, 2);
        rs += __shfl_xor(rs, 4);
        rs += __shfl_xor(rs, 8);
        lrow[mt][rg] = lrow[mt][rg] * alpha + rs;
#pragma unroll
        for (int nt = 0; nt < 8; ++nt) oacc[mt][nt][rg] *= alpha;
      }
    // P -> LDS (wave-private rows)
#pragma unroll
    for (int mt = 0; mt < 2; ++mt)
#pragma unroll
      for (int nt = 0; nt < 4; ++nt)
#pragma unroll
        for (int rg = 0; rg < 4; ++rg)
          Ps[(wave * 32 + mt * 16 + quad * 4 + rg) * 72 + nt * 16 + m16] =
              (__bf16)sacc[mt][nt][rg];
    // O += P V
#pragma unroll
    for (int kc2 = 0; kc2 < 2; ++kc2) {
      bf16x8 af[2];
#pragma unroll
      for (int mt = 0; mt < 2; ++mt)
        af[mt] = *(const bf16x8*)&Ps[(wave * 32 + mt * 16 + m16) * 72 + kc2 * 32 + quad * 8];
#pragma unroll
      for (int nt = 0; nt < 8; ++nt) {
        bf16x8 bv = *(const bf16x8*)&Vt[(nt * 16 + m16) * 72 + kc2 * 32 + quad * 8];
#pragma unroll
        for (int mt = 0; mt < 2; ++mt)
          oacc[mt][nt] = MFMA_BF16(af[mt], bv, oacc[mt][nt]);
      }
    }
  }
  // epilogue
#pragma unroll
  for (int mt = 0; mt < 2; ++mt)
#pragma unroll
    for (int nt = 0; nt < 8; ++nt)
#pragma unroll
      for (int rg = 0; rg < 4; ++rg) {
        int sg = i0 + wave * 32 + mt * 16 + quad * 4 + rg;
        int d = nt * 16 + m16;
        float val = oacc[mt][nt][rg] / lrow[mt][rg];
        Og[((size_t)b * S + sg) * 2048 + h * 128 + d] = (__bf16)val;
      }
}

// ---------------------------------------------------------------------------
extern "C" void kernel_launch(void* const* d_in, const int* in_sizes, int n_in,
                              void* d_out, int out_size, void* d_ws, size_t ws_size,
                              hipStream_t stream) {
  char* w0 = (char*)d_ws;
  int* flag = (int*)w0;
  char* w = w0 + 256;
  __bf16* hid_bf = (__bf16*)w;   w += (size_t)4096 * 5120 * 2;
  __bf16* wqa_bf = (__bf16*)w;   w += (size_t)1536 * 5120 * 2;
  __bf16* wqb_bf = (__bf16*)w;   w += (size_t)3072 * 1536 * 2;
  __bf16* wkva_bf = (__bf16*)w;  w += (size_t)576 * 5120 * 2;
  __bf16* wkvb_bf = (__bf16*)w;  w += (size_t)4096 * 512 * 2;
  __bf16* wo_bf = (__bf16*)w;    w += (size_t)5120 * 2048 * 2;
  __bf16* cos_bf = (__bf16*)w;   w += (size_t)2048 * 64 * 2;
  __bf16* sin_bf = (__bf16*)w;   w += (size_t)2048 * 64 * 2;
  __bf16* qln_bf = (__bf16*)w;   w += 4096;
  __bf16* kvln_bf = (__bf16*)w;  w += 4096;
  float* qa = (float*)w;         w += (size_t)4096 * 1536 * 4;
  __bf16* qan = (__bf16*)w;      w += (size_t)4096 * 1536 * 2;
  __bf16* qb = (__bf16*)w;       w += (size_t)4096 * 3072 * 2;
  float* ckv = (float*)w;        w += (size_t)4096 * 576 * 4;
  __bf16* ckvn = (__bf16*)w;     w += (size_t)4096 * 512 * 2;
  __bf16* kvb = (__bf16*)w;      w += (size_t)4096 * 4096 * 2;
  // Overlays: Qg over hid_bf (dead after gemm kv_a); Kg over wqa_bf+wqb_bf
  // (dead after gemm q_b); ao over qa (dead after rms).
  __bf16* Qg = hid_bf;
  __bf16* Kg = wqa_bf;
  __bf16* ao = (__bf16*)qa;

  sniff_k<<<1, 256, 0, stream>>>((const unsigned int*)d_in[0], flag);
  convert_k<<<1024, 256, 0, stream>>>(d_in[0], hid_bf, (long)4096 * 5120, flag);
  convert_k<<<1024, 256, 0, stream>>>(d_in[3], wqa_bf, (long)1536 * 5120, flag);
  convert_k<<<1024, 256, 0, stream>>>(d_in[5], wqb_bf, (long)3072 * 1536, flag);
  convert_k<<<1024, 256, 0, stream>>>(d_in[6], wkva_bf, (long)576 * 5120, flag);
  convert_k<<<1024, 256, 0, stream>>>(d_in[8], wkvb_bf, (long)4096 * 512, flag);
  convert_k<<<1024, 256, 0, stream>>>(d_in[9], wo_bf, (long)5120 * 2048, flag);
  convert_k<<<64, 256, 0, stream>>>(d_in[10], cos_bf, (long)2048 * 64, flag);
  convert_k<<<64, 256, 0, stream>>>(d_in[11], sin_bf, (long)2048 * 64, flag);
  convert_k<<<2, 256, 0, stream>>>(d_in[4], qln_bf, 1536, flag);
  convert_k<<<1, 256, 0, stream>>>(d_in[7], kvln_bf, 512, flag);

  gemm_bt<128, 0><<<dim3(12, 32), 256, 0, stream>>>(hid_bf, wqa_bf, qa, flag, 4096, 1536, 5120, 5120, 5120, 1536);
  rms_k<1536><<<4096, 256, 0, stream>>>(qa, 1536, qln_bf, qan, 1536);
  gemm_bt<128, 1><<<dim3(24, 32), 256, 0, stream>>>(qan, wqb_bf, qb, flag, 4096, 3072, 1536, 1536, 1536, 3072);
  gemm_bt<64, 0><<<dim3(9, 32), 256, 0, stream>>>(hid_bf, wkva_bf, ckv, flag, 4096, 576, 5120, 5120, 5120, 576);
  rms_k<512><<<4096, 256, 0, stream>>>(ckv, 576, kvln_bf, ckvn, 512);
  gemm_bt<128, 1><<<dim3(32, 32), 256, 0, stream>>>(ckvn, wkvb_bf, kvb, flag, 4096, 4096, 512, 512, 512, 4096);
  prep_k<<<4096, 192, 0, stream>>>(qb, ckv, kvb, cos_bf, sin_bf, Qg, Kg);
  attn_k<<<dim3(16, 32), 256, 0, stream>>>(Qg, Kg, kvb, ao);
  gemm_bt<128, 2><<<dim3(40, 32), 256, 0, stream>>>(ao, wo_bf, d_out, flag, 4096, 5120, 2048, 2048, 2048, 5120);
}